// Round 1
// baseline (1201.238 us; speedup 1.0000x reference)
//
#include <hip/hip_runtime.h>
#include <stdint.h>

typedef __bf16 bf16x8 __attribute__((ext_vector_type(8)));
typedef float f32x4 __attribute__((ext_vector_type(4)));

__device__ __forceinline__ unsigned short f2bf(float f) {
    unsigned int u = __float_as_uint(f);
    unsigned int r = (u + 0x7fffu + ((u >> 16) & 1u)) >> 16;
    return (unsigned short)r;
}
__device__ __forceinline__ float bf2f(unsigned int h) {
    return __uint_as_float(h << 16);
}

__device__ __forceinline__ void gld_lds16(const void* g, void* l) {
    __builtin_amdgcn_global_load_lds((const __attribute__((address_space(1))) void*)g,
                                     (__attribute__((address_space(3))) void*)l, 16, 0, 0);
}

// ---------------- feats f32 -> bf16 (972800 elems, 950 blocks x 256 x 4) ----------------
__global__ __launch_bounds__(256) void k_cvt_feats(const float* __restrict__ src,
                                                   unsigned short* __restrict__ dst) {
    int g = blockIdx.x * 256 + threadIdx.x;
    float4 v = ((const float4*)src)[g];
    ushort4 o;
    o.x = f2bf(v.x); o.y = f2bf(v.y); o.z = f2bf(v.z); o.w = f2bf(v.w);
    ((ushort4*)dst)[g] = o;
}

// ---------------- ROI crop_and_resize(14) + 2x2 maxpool -> pooled bf16 [1024][25088] ----
// block = (roi, pooled cell); thread covers 2 channels.
__global__ __launch_bounds__(256) void k_roipool(const unsigned short* __restrict__ feats,
                                                 const float* __restrict__ props,
                                                 unsigned short* __restrict__ pooled) {
    int b = blockIdx.x;                 // 1024*49
    int r = b / 49;
    int cell = b - r * 49;
    int py = cell / 7, px = cell - py * 7;
    int c = threadIdx.x * 2;
    unsigned int* outp = (unsigned int*)(pooled + (size_t)r * 25088 + cell * 512 + c);
    if (r >= 1000) { *outp = 0u; return; }
    float y1 = props[r * 4 + 0], x1 = props[r * 4 + 1];
    float y2 = props[r * 4 + 2], x2 = props[r * 4 + 3];
    float sy = (y2 - y1) * (37.0f / 13.0f);
    float sx = (x2 - x1) * (49.0f / 13.0f);
    float m0 = -1e30f, m1 = -1e30f;
#pragma unroll
    for (int a = 0; a < 2; ++a) {
        float ys = y1 * 37.0f + (float)(2 * py + a) * sy;
        float y0f = floorf(ys);
        float wy = ys - y0f;
        int y0 = (int)y0f; y0 = min(max(y0, 0), 37);
        int y1i = min(y0 + 1, 37);
#pragma unroll
        for (int bb = 0; bb < 2; ++bb) {
            float xs = x1 * 49.0f + (float)(2 * px + bb) * sx;
            float x0f = floorf(xs);
            float wx = xs - x0f;
            int x0 = (int)x0f; x0 = min(max(x0, 0), 49);
            int x1i = min(x0 + 1, 49);
            unsigned int t00 = *(const unsigned int*)(feats + ((y0 * 50 + x0) * 512 + c));
            unsigned int t01 = *(const unsigned int*)(feats + ((y0 * 50 + x1i) * 512 + c));
            unsigned int t10 = *(const unsigned int*)(feats + ((y1i * 50 + x0) * 512 + c));
            unsigned int t11 = *(const unsigned int*)(feats + ((y1i * 50 + x1i) * 512 + c));
            float w00 = (1.f - wy) * (1.f - wx), w01 = (1.f - wy) * wx;
            float w10 = wy * (1.f - wx), w11 = wy * wx;
            float v0 = bf2f(t00 & 0xffffu) * w00 + bf2f(t01 & 0xffffu) * w01 +
                       bf2f(t10 & 0xffffu) * w10 + bf2f(t11 & 0xffffu) * w11;
            float v1 = bf2f(t00 >> 16) * w00 + bf2f(t01 >> 16) * w01 +
                       bf2f(t10 >> 16) * w10 + bf2f(t11 >> 16) * w11;
            m0 = fmaxf(m0, v0);
            m1 = fmaxf(m1, v1);
        }
    }
    *outp = ((unsigned int)f2bf(m1) << 16) | (unsigned int)f2bf(m0);
}

// ---------------- tiled transpose + f32->bf16: BT[n][k] = bf16(B[k][n]) ----------------
__global__ __launch_bounds__(256) void k_transpose_cvt(const float* __restrict__ B,
                                                       unsigned short* __restrict__ BT,
                                                       int K, int N) {
    __shared__ float tile[64][65];
    int k0 = blockIdx.x * 64;
    int n0 = blockIdx.y * 64;
    int t = threadIdx.x;
    int rr = t >> 4;
    int c4 = (t & 15) * 4;
#pragma unroll
    for (int ii = 0; ii < 4; ++ii) {
        int r = rr + ii * 16;
        float4 v = *(const float4*)(B + (size_t)(k0 + r) * N + n0 + c4);
        tile[r][c4 + 0] = v.x; tile[r][c4 + 1] = v.y;
        tile[r][c4 + 2] = v.z; tile[r][c4 + 3] = v.w;
    }
    __syncthreads();
    int nl = t >> 2;
    int ks = (t & 3) * 16;
    union { unsigned short us[16]; uint4 q[2]; } u;
#pragma unroll
    for (int j = 0; j < 16; ++j) u.us[j] = f2bf(tile[ks + j][nl]);
    uint4* dst = (uint4*)(BT + (size_t)(n0 + nl) * K + k0 + ks);
    dst[0] = u.q[0];
    dst[1] = u.q[1];
}

// ---------------- m97-style bf16 GEMM, 128x128 tile, BK=32, split-K atomics ------------
// A [M,K] bf16 row-major; BT [N,K] bf16 row-major; C [M,N] f32 accumulated via atomicAdd.
__global__ __launch_bounds__(256) void k_gemm(const unsigned short* __restrict__ A,
                                              const unsigned short* __restrict__ BT,
                                              float* __restrict__ C,
                                              int N, int K, int kChunk) {
    __shared__ __align__(16) unsigned short As[128 * 32];
    __shared__ __align__(16) unsigned short Bs[128 * 32];
    const int n0 = blockIdx.x * 128;
    const int m0 = blockIdx.y * 128;
    const int kBeg = blockIdx.z * kChunk;
    const int kEnd = kBeg + kChunk;
    const int t = threadIdx.x;
    const int lane = t & 63;
    const int wave = t >> 6;
    const int wm = (wave & 1) * 64;
    const int wn = (wave >> 1) * 64;
    const int l15 = lane & 15;
    const int k8 = (lane >> 4) * 8;

    const int c0 = t, c1 = t + 256;
    const unsigned short* agp0 = A + (size_t)(m0 + (c0 >> 2)) * K + (c0 & 3) * 8;
    const unsigned short* agp1 = A + (size_t)(m0 + (c1 >> 2)) * K + (c1 & 3) * 8;
    const unsigned short* bgp0 = BT + (size_t)(n0 + (c0 >> 2)) * K + (c0 & 3) * 8;
    const unsigned short* bgp1 = BT + (size_t)(n0 + (c1 >> 2)) * K + (c1 & 3) * 8;
    char* al0 = (char*)As + (c0 & ~63) * 16;
    char* al1 = (char*)As + (c1 & ~63) * 16;
    char* bl0 = (char*)Bs + (c0 & ~63) * 16;
    char* bl1 = (char*)Bs + (c1 & ~63) * 16;

    f32x4 acc[4][4] = {};
    const unsigned short* aF = As + (wm + l15) * 32 + k8;
    const unsigned short* bF = Bs + (wn + l15) * 32 + k8;

    for (int kt = kBeg; kt < kEnd; kt += 32) {
        gld_lds16(agp0 + kt, al0);
        gld_lds16(agp1 + kt, al1);
        gld_lds16(bgp0 + kt, bl0);
        gld_lds16(bgp1 + kt, bl1);
        __syncthreads();
        bf16x8 av[4], bv[4];
#pragma unroll
        for (int i = 0; i < 4; ++i) av[i] = *(const bf16x8*)(aF + i * 16 * 32);
#pragma unroll
        for (int j = 0; j < 4; ++j) bv[j] = *(const bf16x8*)(bF + j * 16 * 32);
#pragma unroll
        for (int i = 0; i < 4; ++i)
#pragma unroll
            for (int j = 0; j < 4; ++j)
                acc[i][j] = __builtin_amdgcn_mfma_f32_16x16x32_bf16(av[i], bv[j], acc[i][j], 0, 0, 0);
        __syncthreads();
    }

    const int row_b = m0 + wm + (lane >> 4) * 4;
    const int col_b = n0 + wn + l15;
#pragma unroll
    for (int i = 0; i < 4; ++i)
#pragma unroll
        for (int j = 0; j < 4; ++j)
#pragma unroll
            for (int r = 0; r < 4; ++r)
                atomicAdd(C + (size_t)(row_b + i * 16 + r) * N + (col_b + j * 16), acc[i][j][r]);
}

// ---------------- acc + bias -> relu -> bf16; re-zero acc ------------------------------
__global__ __launch_bounds__(256) void k_bias_relu_cvt(float* __restrict__ acc,
                                                       const float* __restrict__ bias,
                                                       unsigned short* __restrict__ out) {
    int g = blockIdx.x * 256 + threadIdx.x;   // 1024*4096/4 = 1048576 -> 4096 blocks
    float4 v = ((float4*)acc)[g];
    float4 b = ((const float4*)bias)[g & 1023];
    ushort4 o;
    o.x = f2bf(fmaxf(v.x + b.x, 0.f));
    o.y = f2bf(fmaxf(v.y + b.y, 0.f));
    o.z = f2bf(fmaxf(v.z + b.z, 0.f));
    o.w = f2bf(fmaxf(v.w + b.w, 0.f));
    ((ushort4*)out)[g] = o;
    ((float4*)acc)[g] = make_float4(0.f, 0.f, 0.f, 0.f);
}

// ---------------- pack Wc (21) and Wr (80) transposed into [128][4096] bf16 ------------
__global__ __launch_bounds__(256) void k_pack_w3(const float* __restrict__ Wc,
                                                 const float* __restrict__ Wr,
                                                 unsigned short* __restrict__ W3T) {
    int g = blockIdx.x * 256 + threadIdx.x;   // 128*4096 -> 2048 blocks
    int n = g >> 12, k = g & 4095;
    float v = 0.f;
    if (n < 21) v = Wc[k * 21 + n];
    else if (n < 101) v = Wr[k * 80 + (n - 21)];
    W3T[g] = f2bf(v);
}

// ---------------- softmax(cls) + reg writeout; one wave per roi ------------------------
__global__ __launch_bounds__(64) void k_head(const float* __restrict__ acc3,
                                             const float* __restrict__ bc,
                                             const float* __restrict__ br,
                                             float* __restrict__ out) {
    int r = blockIdx.x;          // 1000
    int lane = threadIdx.x;      // 64
    const float* rowp = acc3 + r * 128;
    float logit = (lane < 21) ? rowp[lane] + bc[lane] : -1e30f;
    float mx = logit;
#pragma unroll
    for (int m = 32; m >= 1; m >>= 1) mx = fmaxf(mx, __shfl_xor(mx, m, 64));
    float e = (lane < 21) ? expf(logit - mx) : 0.f;
    float s = e;
#pragma unroll
    for (int m = 32; m >= 1; m >>= 1) s += __shfl_xor(s, m, 64);
    if (lane < 21) out[r * 21 + lane] = e / s;
    for (int j = lane; j < 80; j += 64)
        out[21000 + r * 80 + j] = rowp[21 + j] + br[j];
}

extern "C" void kernel_launch(void* const* d_in, const int* in_sizes, int n_in,
                              void* d_out, int out_size, void* d_ws, size_t ws_size,
                              hipStream_t stream) {
    (void)in_sizes; (void)n_in; (void)out_size; (void)ws_size;
    const float* feats = (const float*)d_in[0];
    const float* props = (const float*)d_in[1];
    const float* W1    = (const float*)d_in[2];
    const float* b1    = (const float*)d_in[3];
    const float* W2    = (const float*)d_in[4];
    const float* b2    = (const float*)d_in[5];
    const float* Wc    = (const float*)d_in[6];
    const float* bc    = (const float*)d_in[7];
    const float* Wr    = (const float*)d_in[8];
    const float* br    = (const float*)d_in[9];
    float* out = (float*)d_out;

    char* ws = (char*)d_ws;
    unsigned short* W1T    = (unsigned short*)ws; ws += (size_t)4096 * 25088 * 2; // 205.5 MB
    unsigned short* W2T    = (unsigned short*)ws; ws += (size_t)4096 * 4096 * 2;  // 33.6 MB
    unsigned short* W3T    = (unsigned short*)ws; ws += (size_t)128 * 4096 * 2;   // 1.05 MB
    unsigned short* featsb = (unsigned short*)ws; ws += (size_t)972800 * 2;       // 1.95 MB
    unsigned short* pooled = (unsigned short*)ws; ws += (size_t)1024 * 25088 * 2; // 51.4 MB
    unsigned short* x1     = (unsigned short*)ws; ws += (size_t)1024 * 4096 * 2;  // 8.4 MB
    unsigned short* x2     = (unsigned short*)ws; ws += (size_t)1024 * 4096 * 2;  // 8.4 MB
    float* acc             = (float*)ws;          ws += (size_t)1024 * 4096 * 4;  // 16.8 MB
    float* acc3            = (float*)ws;          ws += (size_t)1024 * 128 * 4;   // 0.5 MB

    hipMemsetAsync(acc, 0, (size_t)1024 * 4096 * 4, stream);
    hipMemsetAsync(acc3, 0, (size_t)1024 * 128 * 4, stream);

    k_cvt_feats<<<950, 256, 0, stream>>>(feats, featsb);
    k_roipool<<<1024 * 49, 256, 0, stream>>>(featsb, props, pooled);
    k_transpose_cvt<<<dim3(392, 64), 256, 0, stream>>>(W1, W1T, 25088, 4096);
    k_gemm<<<dim3(32, 8, 4), 256, 0, stream>>>(pooled, W1T, acc, 4096, 25088, 6272);
    k_bias_relu_cvt<<<4096, 256, 0, stream>>>(acc, b1, x1);
    k_transpose_cvt<<<dim3(64, 64), 256, 0, stream>>>(W2, W2T, 4096, 4096);
    k_gemm<<<dim3(32, 8, 4), 256, 0, stream>>>(x1, W2T, acc, 4096, 4096, 1024);
    k_bias_relu_cvt<<<4096, 256, 0, stream>>>(acc, b2, x2);
    k_pack_w3<<<2048, 256, 0, stream>>>(Wc, Wr, W3T);
    k_gemm<<<dim3(1, 8, 16), 256, 0, stream>>>(x2, W3T, acc3, 128, 4096, 256);
    k_head<<<1000, 64, 0, stream>>>(acc3, bc, br, out);
}

// Round 2
// 1076.194 us; speedup vs baseline: 1.1162x; 1.1162x over previous
//
#include <hip/hip_runtime.h>
#include <stdint.h>

typedef __bf16 bf16x8 __attribute__((ext_vector_type(8)));
typedef float f32x4 __attribute__((ext_vector_type(4)));

__device__ __forceinline__ unsigned short f2bf(float f) {
    unsigned int u = __float_as_uint(f);
    unsigned int r = (u + 0x7fffu + ((u >> 16) & 1u)) >> 16;
    return (unsigned short)r;
}
__device__ __forceinline__ float bf2f(unsigned int h) {
    return __uint_as_float(h << 16);
}

__device__ __forceinline__ void gld_lds16(const void* g, void* l) {
    __builtin_amdgcn_global_load_lds((const __attribute__((address_space(1))) void*)g,
                                     (__attribute__((address_space(3))) void*)l, 16, 0, 0);
}

// ---------------- feats f32 -> bf16 ----------------------------------------------------
__global__ __launch_bounds__(256) void k_cvt_feats(const float* __restrict__ src,
                                                   unsigned short* __restrict__ dst) {
    int g = blockIdx.x * 256 + threadIdx.x;
    float4 v = ((const float4*)src)[g];
    ushort4 o;
    o.x = f2bf(v.x); o.y = f2bf(v.y); o.z = f2bf(v.z); o.w = f2bf(v.w);
    ((ushort4*)dst)[g] = o;
}

// ---------------- ROI crop_and_resize(14) + 2x2 maxpool -> pooled bf16 [1024][25088] ----
__global__ __launch_bounds__(256) void k_roipool(const unsigned short* __restrict__ feats,
                                                 const float* __restrict__ props,
                                                 unsigned short* __restrict__ pooled) {
    int b = blockIdx.x;                 // 1024*49
    int r = b / 49;
    int cell = b - r * 49;
    int py = cell / 7, px = cell - py * 7;
    int c = threadIdx.x * 2;
    unsigned int* outp = (unsigned int*)(pooled + (size_t)r * 25088 + cell * 512 + c);
    if (r >= 1000) { *outp = 0u; return; }
    float y1 = props[r * 4 + 0], x1 = props[r * 4 + 1];
    float y2 = props[r * 4 + 2], x2 = props[r * 4 + 3];
    float sy = (y2 - y1) * (37.0f / 13.0f);
    float sx = (x2 - x1) * (49.0f / 13.0f);
    float m0 = -1e30f, m1 = -1e30f;
#pragma unroll
    for (int a = 0; a < 2; ++a) {
        float ys = y1 * 37.0f + (float)(2 * py + a) * sy;
        float y0f = floorf(ys);
        float wy = ys - y0f;
        int y0 = (int)y0f; y0 = min(max(y0, 0), 37);
        int y1i = min(y0 + 1, 37);
#pragma unroll
        for (int bb = 0; bb < 2; ++bb) {
            float xs = x1 * 49.0f + (float)(2 * px + bb) * sx;
            float x0f = floorf(xs);
            float wx = xs - x0f;
            int x0 = (int)x0f; x0 = min(max(x0, 0), 49);
            int x1i = min(x0 + 1, 49);
            unsigned int t00 = *(const unsigned int*)(feats + ((y0 * 50 + x0) * 512 + c));
            unsigned int t01 = *(const unsigned int*)(feats + ((y0 * 50 + x1i) * 512 + c));
            unsigned int t10 = *(const unsigned int*)(feats + ((y1i * 50 + x0) * 512 + c));
            unsigned int t11 = *(const unsigned int*)(feats + ((y1i * 50 + x1i) * 512 + c));
            float w00 = (1.f - wy) * (1.f - wx), w01 = (1.f - wy) * wx;
            float w10 = wy * (1.f - wx), w11 = wy * wx;
            float v0 = bf2f(t00 & 0xffffu) * w00 + bf2f(t01 & 0xffffu) * w01 +
                       bf2f(t10 & 0xffffu) * w10 + bf2f(t11 & 0xffffu) * w11;
            float v1 = bf2f(t00 >> 16) * w00 + bf2f(t01 >> 16) * w01 +
                       bf2f(t10 >> 16) * w10 + bf2f(t11 >> 16) * w11;
            m0 = fmaxf(m0, v0);
            m1 = fmaxf(m1, v1);
        }
    }
    *outp = ((unsigned int)f2bf(m1) << 16) | (unsigned int)f2bf(m0);
}

// ---------------- tiled transpose + f32->bf16: BT[n][k] = bf16(B[k][n]) ----------------
// LDS holds bf16 PAIRS (k even|odd packed in u32), layout [n][k/2], row stride 34 dwords.
__global__ __launch_bounds__(256) void k_transpose_cvt(const float* __restrict__ B,
                                                       unsigned short* __restrict__ BT,
                                                       int K, int N) {
    __shared__ unsigned int tile[64][34];
    int k0 = blockIdx.x * 64;
    int n0 = blockIdx.y * 64;
    int t = threadIdx.x;
    int kr = (t >> 4) * 2;        // even k within tile: 0..30
    int c4 = (t & 15) * 4;        // n within tile
#pragma unroll
    for (int ii = 0; ii < 2; ++ii) {
        int k = kr + ii * 32;
        const float* p0 = B + (size_t)(k0 + k) * N + n0 + c4;
        float4 v0 = *(const float4*)p0;
        float4 v1 = *(const float4*)(p0 + N);
        tile[c4 + 0][k >> 1] = (unsigned)f2bf(v0.x) | ((unsigned)f2bf(v1.x) << 16);
        tile[c4 + 1][k >> 1] = (unsigned)f2bf(v0.y) | ((unsigned)f2bf(v1.y) << 16);
        tile[c4 + 2][k >> 1] = (unsigned)f2bf(v0.z) | ((unsigned)f2bf(v1.z) << 16);
        tile[c4 + 3][k >> 1] = (unsigned)f2bf(v0.w) | ((unsigned)f2bf(v1.w) << 16);
    }
    __syncthreads();
    int nl = t >> 2;
    int kb = (t & 3) * 8;         // dword index within row
    uint2 r0 = *(const uint2*)&tile[nl][kb + 0];
    uint2 r1 = *(const uint2*)&tile[nl][kb + 2];
    uint2 r2 = *(const uint2*)&tile[nl][kb + 4];
    uint2 r3 = *(const uint2*)&tile[nl][kb + 6];
    unsigned short* dst = BT + (size_t)(n0 + nl) * K + k0 + (t & 3) * 16;
    *(uint2*)(dst + 0) = r0;
    *(uint2*)(dst + 4) = r1;
    *(uint2*)(dst + 8) = r2;
    *(uint2*)(dst + 12) = r3;
}

// ---------------- bf16 GEMM, 128x128 tile, BK=64, XOR-swizzled LDS, split-K partials ---
// A [M,K] bf16 rm; BT [N,K] bf16 rm; Cpart[z][M][N] f32 (overwritten, no atomics).
__global__ __launch_bounds__(256) void k_gemm(const unsigned short* __restrict__ A,
                                              const unsigned short* __restrict__ BT,
                                              float* __restrict__ Cpart,
                                              int N, int K, int kChunk, int MN) {
    __shared__ __align__(16) unsigned short As[128 * 64];
    __shared__ __align__(16) unsigned short Bs[128 * 64];
    const int n0 = blockIdx.x * 128;
    const int m0 = blockIdx.y * 128;
    const int kBeg = blockIdx.z * kChunk;
    const int kEnd = kBeg + kChunk;
    const int t = threadIdx.x;
    const int lane = t & 63;
    const int wave = t >> 6;
    const int wm = (wave & 1) * 64;
    const int wn = (wave >> 1) * 64;
    const int l15 = lane & 15;
    const int g   = lane >> 4;          // k-group 0..3
    const int xorb = l15 & 7;

    // staging: chunk c = t + 256*q; row = c>>3, chunk-col jc = c&7 holds source
    // k-chunk (jc ^ (row&7)) -- XOR swizzle breaks the 8-way fragment-read conflict.
    const int srow = t >> 3;
    const int sj = (t & 7) ^ (srow & 7);
    const unsigned short* ag = A + (size_t)(m0 + srow) * K + sj * 8;
    const unsigned short* bg = BT + (size_t)(n0 + srow) * K + sj * 8;
    char* alb = (char*)As + (t & ~63) * 16;
    char* blb = (char*)Bs + (t & ~63) * 16;
    const int rq = K * 32;              // +32 rows per q-step

    f32x4 acc[4][4] = {};
    const unsigned short* aBase = As + (wm + l15) * 64;
    const unsigned short* bBase = Bs + (wn + l15) * 64;

    for (int kt = kBeg; kt < kEnd; kt += 64) {
#pragma unroll
        for (int q = 0; q < 4; ++q) gld_lds16(ag + kt + q * rq, alb + q * 4096);
#pragma unroll
        for (int q = 0; q < 4; ++q) gld_lds16(bg + kt + q * rq, blb + q * 4096);
        __syncthreads();
#pragma unroll
        for (int s = 0; s < 2; ++s) {
            const int off = ((s * 4 + g) ^ xorb) * 8;
            bf16x8 av[4], bv[4];
#pragma unroll
            for (int i = 0; i < 4; ++i) av[i] = *(const bf16x8*)(aBase + i * 1024 + off);
#pragma unroll
            for (int j = 0; j < 4; ++j) bv[j] = *(const bf16x8*)(bBase + j * 1024 + off);
#pragma unroll
            for (int i = 0; i < 4; ++i)
#pragma unroll
                for (int j = 0; j < 4; ++j)
                    acc[i][j] = __builtin_amdgcn_mfma_f32_16x16x32_bf16(av[i], bv[j], acc[i][j], 0, 0, 0);
        }
        __syncthreads();
    }

    float* Cp = Cpart + (size_t)blockIdx.z * MN;
    const int row_b = m0 + wm + (lane >> 4) * 4;
    const int col_b = n0 + wn + l15;
#pragma unroll
    for (int i = 0; i < 4; ++i)
#pragma unroll
        for (int j = 0; j < 4; ++j)
#pragma unroll
            for (int r = 0; r < 4; ++r)
                Cp[(size_t)(row_b + i * 16 + r) * N + (col_b + j * 16)] = acc[i][j][r];
}

// ---------------- 4-partial reduce + bias -> relu -> bf16 ------------------------------
__global__ __launch_bounds__(256) void k_bias_relu_cvt(const float* __restrict__ accP,
                                                       const float* __restrict__ bias,
                                                       unsigned short* __restrict__ out) {
    int gI = blockIdx.x * 256 + threadIdx.x;   // 1048576 float4s
    const float4* p = (const float4*)accP;
    float4 v0 = p[gI];
    float4 v1 = p[gI + 1048576];
    float4 v2 = p[gI + 2097152];
    float4 v3 = p[gI + 3145728];
    float4 b = ((const float4*)bias)[gI & 1023];
    ushort4 o;
    o.x = f2bf(fmaxf(v0.x + v1.x + v2.x + v3.x + b.x, 0.f));
    o.y = f2bf(fmaxf(v0.y + v1.y + v2.y + v3.y + b.y, 0.f));
    o.z = f2bf(fmaxf(v0.z + v1.z + v2.z + v3.z + b.z, 0.f));
    o.w = f2bf(fmaxf(v0.w + v1.w + v2.w + v3.w + b.w, 0.f));
    ((ushort4*)out)[gI] = o;
}

// ---------------- pack Wc (21) and Wr (80) transposed into [128][4096] bf16 ------------
__global__ __launch_bounds__(256) void k_pack_w3(const float* __restrict__ Wc,
                                                 const float* __restrict__ Wr,
                                                 unsigned short* __restrict__ W3T) {
    int gI = blockIdx.x * 256 + threadIdx.x;   // 128*4096
    int n = gI >> 12, k = gI & 4095;
    float v = 0.f;
    if (n < 21) v = Wc[k * 21 + n];
    else if (n < 101) v = Wr[k * 80 + (n - 21)];
    W3T[gI] = f2bf(v);
}

// ---------------- 16-partial reduce + softmax(cls) + reg writeout ----------------------
__global__ __launch_bounds__(64) void k_head(const float* __restrict__ acc3,
                                             const float* __restrict__ bc,
                                             const float* __restrict__ br,
                                             float* __restrict__ out) {
    int r = blockIdx.x;          // 1000
    int lane = threadIdx.x;
    float logit = -1e30f;
    if (lane < 21) {
        logit = bc[lane];
#pragma unroll
        for (int z = 0; z < 16; ++z) logit += acc3[z * 131072 + r * 128 + lane];
    }
    float mx = logit;
#pragma unroll
    for (int m = 32; m >= 1; m >>= 1) mx = fmaxf(mx, __shfl_xor(mx, m, 64));
    float e = (lane < 21) ? expf(logit - mx) : 0.f;
    float s = e;
#pragma unroll
    for (int m = 32; m >= 1; m >>= 1) s += __shfl_xor(s, m, 64);
    if (lane < 21) out[r * 21 + lane] = e / s;
    for (int j = lane; j < 80; j += 64) {
        float v = br[j];
#pragma unroll
        for (int z = 0; z < 16; ++z) v += acc3[z * 131072 + r * 128 + 21 + j];
        out[21000 + r * 80 + j] = v;
    }
}

extern "C" void kernel_launch(void* const* d_in, const int* in_sizes, int n_in,
                              void* d_out, int out_size, void* d_ws, size_t ws_size,
                              hipStream_t stream) {
    (void)in_sizes; (void)n_in; (void)out_size; (void)ws_size;
    const float* feats = (const float*)d_in[0];
    const float* props = (const float*)d_in[1];
    const float* W1    = (const float*)d_in[2];
    const float* b1    = (const float*)d_in[3];
    const float* W2    = (const float*)d_in[4];
    const float* b2    = (const float*)d_in[5];
    const float* Wc    = (const float*)d_in[6];
    const float* bc    = (const float*)d_in[7];
    const float* Wr    = (const float*)d_in[8];
    const float* br    = (const float*)d_in[9];
    float* out = (float*)d_out;

    char* ws = (char*)d_ws;
    unsigned short* W1T    = (unsigned short*)ws; ws += (size_t)4096 * 25088 * 2; // 205.5 MB
    unsigned short* W2T    = (unsigned short*)ws; ws += (size_t)4096 * 4096 * 2;  // 33.6 MB
    unsigned short* W3T    = (unsigned short*)ws; ws += (size_t)128 * 4096 * 2;   // 1.05 MB
    unsigned short* featsb = (unsigned short*)ws; ws += (size_t)972800 * 2;       // 1.95 MB
    unsigned short* pooled = (unsigned short*)ws; ws += (size_t)1024 * 25088 * 2; // 51.4 MB
    unsigned short* x1     = (unsigned short*)ws; ws += (size_t)1024 * 4096 * 2;  // 8.4 MB
    unsigned short* x2     = (unsigned short*)ws; ws += (size_t)1024 * 4096 * 2;  // 8.4 MB
    float* accP            = (float*)ws;          ws += (size_t)4 * 1024 * 4096 * 4; // 67.1 MB
    float* acc3P           = accP;  // GEMM3 partials reuse accP (free after bias2)

    k_cvt_feats<<<950, 256, 0, stream>>>(feats, featsb);
    k_roipool<<<1024 * 49, 256, 0, stream>>>(featsb, props, pooled);
    k_transpose_cvt<<<dim3(392, 64), 256, 0, stream>>>(W1, W1T, 25088, 4096);
    k_gemm<<<dim3(32, 8, 4), 256, 0, stream>>>(pooled, W1T, accP, 4096, 25088, 6272, 1024 * 4096);
    k_bias_relu_cvt<<<4096, 256, 0, stream>>>(accP, b1, x1);
    k_transpose_cvt<<<dim3(64, 64), 256, 0, stream>>>(W2, W2T, 4096, 4096);
    k_gemm<<<dim3(32, 8, 4), 256, 0, stream>>>(x1, W2T, accP, 4096, 4096, 1024, 1024 * 4096);
    k_bias_relu_cvt<<<4096, 256, 0, stream>>>(accP, b2, x2);
    k_pack_w3<<<2048, 256, 0, stream>>>(Wc, Wr, W3T);
    k_gemm<<<dim3(1, 8, 16), 256, 0, stream>>>(x2, W3T, acc3P, 128, 4096, 256, 1024 * 128);
    k_head<<<1000, 64, 0, stream>>>(acc3P, bc, br, out);
}

// Round 3
// 997.876 us; speedup vs baseline: 1.2038x; 1.0785x over previous
//
#include <hip/hip_runtime.h>
#include <stdint.h>

typedef __bf16 bf16x8 __attribute__((ext_vector_type(8)));
typedef float f32x16 __attribute__((ext_vector_type(16)));

__device__ __forceinline__ unsigned short f2bf(float f) {
    unsigned int u = __float_as_uint(f);
    unsigned int r = (u + 0x7fffu + ((u >> 16) & 1u)) >> 16;
    return (unsigned short)r;
}
__device__ __forceinline__ float bf2f(unsigned int h) {
    return __uint_as_float(h << 16);
}

__device__ __forceinline__ void gld_lds16(const void* g, void* l) {
    __builtin_amdgcn_global_load_lds((const __attribute__((address_space(1))) void*)g,
                                     (__attribute__((address_space(3))) void*)l, 16, 0, 0);
}

// ---------------- feats f32 -> bf16 ----------------------------------------------------
__global__ __launch_bounds__(256) void k_cvt_feats(const float* __restrict__ src,
                                                   unsigned short* __restrict__ dst) {
    int g = blockIdx.x * 256 + threadIdx.x;
    float4 v = ((const float4*)src)[g];
    ushort4 o;
    o.x = f2bf(v.x); o.y = f2bf(v.y); o.z = f2bf(v.z); o.w = f2bf(v.w);
    ((ushort4*)dst)[g] = o;
}

// ---------------- ROI crop_and_resize(14) + 2x2 maxpool -> pooled bf16 [1024][25088] ----
__global__ __launch_bounds__(256) void k_roipool(const unsigned short* __restrict__ feats,
                                                 const float* __restrict__ props,
                                                 unsigned short* __restrict__ pooled) {
    int b = blockIdx.x;                 // 1024*49
    int r = b / 49;
    int cell = b - r * 49;
    int py = cell / 7, px = cell - py * 7;
    int c = threadIdx.x * 2;
    unsigned int* outp = (unsigned int*)(pooled + (size_t)r * 25088 + cell * 512 + c);
    if (r >= 1000) { *outp = 0u; return; }
    float y1 = props[r * 4 + 0], x1 = props[r * 4 + 1];
    float y2 = props[r * 4 + 2], x2 = props[r * 4 + 3];
    float sy = (y2 - y1) * (37.0f / 13.0f);
    float sx = (x2 - x1) * (49.0f / 13.0f);
    float m0 = -1e30f, m1 = -1e30f;
#pragma unroll
    for (int a = 0; a < 2; ++a) {
        float ys = y1 * 37.0f + (float)(2 * py + a) * sy;
        float y0f = floorf(ys);
        float wy = ys - y0f;
        int y0 = (int)y0f; y0 = min(max(y0, 0), 37);
        int y1i = min(y0 + 1, 37);
#pragma unroll
        for (int bb = 0; bb < 2; ++bb) {
            float xs = x1 * 49.0f + (float)(2 * px + bb) * sx;
            float x0f = floorf(xs);
            float wx = xs - x0f;
            int x0 = (int)x0f; x0 = min(max(x0, 0), 49);
            int x1i = min(x0 + 1, 49);
            unsigned int t00 = *(const unsigned int*)(feats + ((y0 * 50 + x0) * 512 + c));
            unsigned int t01 = *(const unsigned int*)(feats + ((y0 * 50 + x1i) * 512 + c));
            unsigned int t10 = *(const unsigned int*)(feats + ((y1i * 50 + x0) * 512 + c));
            unsigned int t11 = *(const unsigned int*)(feats + ((y1i * 50 + x1i) * 512 + c));
            float w00 = (1.f - wy) * (1.f - wx), w01 = (1.f - wy) * wx;
            float w10 = wy * (1.f - wx), w11 = wy * wx;
            float v0 = bf2f(t00 & 0xffffu) * w00 + bf2f(t01 & 0xffffu) * w01 +
                       bf2f(t10 & 0xffffu) * w10 + bf2f(t11 & 0xffffu) * w11;
            float v1 = bf2f(t00 >> 16) * w00 + bf2f(t01 >> 16) * w01 +
                       bf2f(t10 >> 16) * w10 + bf2f(t11 >> 16) * w11;
            m0 = fmaxf(m0, v0);
            m1 = fmaxf(m1, v1);
        }
    }
    *outp = ((unsigned int)f2bf(m1) << 16) | (unsigned int)f2bf(m0);
}

// ---------------- tiled transpose + f32->bf16: BT[n][k] = bf16(B[k][n]) ----------------
// LDS: bf16 pairs (k even|odd in u32), [64 n][32 dw], pair-granule XOR swizzle (no pad):
// dword kd of row n lives at ((kd>>1) ^ ((n>>2)&7))*2 + (kd&1).
__global__ __launch_bounds__(256) void k_transpose_cvt(const float* __restrict__ B,
                                                       unsigned short* __restrict__ BT,
                                                       int K, int N) {
    __shared__ unsigned int tile[64][32];
    int k0 = blockIdx.x * 64;
    int n0 = blockIdx.y * 64;
    int t = threadIdx.x;
    int kr = (t >> 4) * 2;        // even k within tile: 0..30
    int c4 = (t & 15) * 4;        // n within tile
#pragma unroll
    for (int ii = 0; ii < 2; ++ii) {
        int k = kr + ii * 32;
        int kd = k >> 1;
        const float* p0 = B + (size_t)(k0 + k) * N + n0 + c4;
        float4 v0 = *(const float4*)p0;
        float4 v1 = *(const float4*)(p0 + N);
        float lo[4] = {v0.x, v0.y, v0.z, v0.w};
        float hi[4] = {v1.x, v1.y, v1.z, v1.w};
#pragma unroll
        for (int c = 0; c < 4; ++c) {
            int n = c4 + c;
            int dw = (((kd >> 1) ^ ((n >> 2) & 7)) << 1) | (kd & 1);
            tile[n][dw] = (unsigned)f2bf(lo[c]) | ((unsigned)f2bf(hi[c]) << 16);
        }
    }
    __syncthreads();
    int nl = t >> 2;
    int x = (nl >> 2) & 7;
    int pbase = (t & 3) * 4;      // original pair index base
    uint2 r[4];
#pragma unroll
    for (int q = 0; q < 4; ++q) {
        int p = (pbase + q) ^ x;
        r[q] = *(const uint2*)&tile[nl][p << 1];
    }
    unsigned short* dst = BT + (size_t)(n0 + nl) * K + k0 + (t & 3) * 16;
    uint4 o0, o1;
    o0.x = r[0].x; o0.y = r[0].y; o0.z = r[1].x; o0.w = r[1].y;
    o1.x = r[2].x; o1.y = r[2].y; o1.z = r[3].x; o1.w = r[3].y;
    *(uint4*)(dst + 0) = o0;
    *(uint4*)(dst + 8) = o1;
}

// ---------------- bf16 GEMM, 128x128 tile, BK=64, 32x32x16 MFMA, split-K partials ------
// A [M,K] bf16 rm; BT [N,K] bf16 rm; Cpart[z][M][N] f32 (overwritten, no atomics).
__global__ __launch_bounds__(256) void k_gemm(const unsigned short* __restrict__ A,
                                              const unsigned short* __restrict__ BT,
                                              float* __restrict__ Cpart,
                                              int N, int K, int kChunk, int MN) {
    __shared__ __align__(16) unsigned short As[128 * 64];
    __shared__ __align__(16) unsigned short Bs[128 * 64];
    const int n0 = blockIdx.x * 128;
    const int m0 = blockIdx.y * 128;
    const int kBeg = blockIdx.z * kChunk;
    const int kEnd = kBeg + kChunk;
    const int t = threadIdx.x;
    const int lane = t & 63;
    const int wave = t >> 6;
    const int wm = (wave & 1) * 64;
    const int wn = (wave >> 1) * 64;
    const int l31 = lane & 31;
    const int half = lane >> 5;         // k-half 0..1
    const int xorb = l31 & 7;

    // staging: row = t>>3, chunk-col jc = t&7 stores source k-chunk (jc ^ (row&7)).
    const int srow = t >> 3;
    const int sj = (t & 7) ^ (srow & 7);
    const unsigned short* ag = A + (size_t)(m0 + srow) * K + sj * 8;
    const unsigned short* bg = BT + (size_t)(n0 + srow) * K + sj * 8;
    char* alb = (char*)As + t * 16;
    char* blb = (char*)Bs + t * 16;
    const int rq = K * 32;              // +32 rows per q-step

    f32x16 acc[2][2] = {};
    const unsigned short* aBase = As + (wm + l31) * 64;
    const unsigned short* bBase = Bs + (wn + l31) * 64;

    for (int kt = kBeg; kt < kEnd; kt += 64) {
#pragma unroll
        for (int q = 0; q < 4; ++q) gld_lds16(ag + kt + q * rq, alb + q * 4096);
#pragma unroll
        for (int q = 0; q < 4; ++q) gld_lds16(bg + kt + q * rq, blb + q * 4096);
        __syncthreads();
#pragma unroll
        for (int s = 0; s < 4; ++s) {   // K=16 per step
            const int off = ((s * 2 + half) ^ xorb) * 8;
            bf16x8 a0 = *(const bf16x8*)(aBase + off);
            bf16x8 a1 = *(const bf16x8*)(aBase + 2048 + off);
            bf16x8 b0 = *(const bf16x8*)(bBase + off);
            bf16x8 b1 = *(const bf16x8*)(bBase + 2048 + off);
            acc[0][0] = __builtin_amdgcn_mfma_f32_32x32x16_bf16(a0, b0, acc[0][0], 0, 0, 0);
            acc[0][1] = __builtin_amdgcn_mfma_f32_32x32x16_bf16(a0, b1, acc[0][1], 0, 0, 0);
            acc[1][0] = __builtin_amdgcn_mfma_f32_32x32x16_bf16(a1, b0, acc[1][0], 0, 0, 0);
            acc[1][1] = __builtin_amdgcn_mfma_f32_32x32x16_bf16(a1, b1, acc[1][1], 0, 0, 0);
        }
        __syncthreads();
    }

    // C/D layout: col = lane&31, row = (reg&3) + 8*(reg>>2) + 4*(lane>>5)
    float* Cp = Cpart + (size_t)blockIdx.z * MN;
    const int colb = n0 + wn + l31;
    const int rbase = m0 + wm + 4 * half;
#pragma unroll
    for (int i = 0; i < 2; ++i)
#pragma unroll
        for (int j = 0; j < 2; ++j)
#pragma unroll
            for (int reg = 0; reg < 16; ++reg) {
                int row = rbase + i * 32 + (reg & 3) + 8 * (reg >> 2);
                Cp[(size_t)row * N + colb + j * 32] = acc[i][j][reg];
            }
}

// ---------------- 4-partial reduce + bias -> relu -> bf16 ------------------------------
__global__ __launch_bounds__(256) void k_bias_relu_cvt(const float* __restrict__ accP,
                                                       const float* __restrict__ bias,
                                                       unsigned short* __restrict__ out) {
    int gI = blockIdx.x * 256 + threadIdx.x;   // 1048576 float4s
    const float4* p = (const float4*)accP;
    float4 v0 = p[gI];
    float4 v1 = p[gI + 1048576];
    float4 v2 = p[gI + 2097152];
    float4 v3 = p[gI + 3145728];
    float4 b = ((const float4*)bias)[gI & 1023];
    ushort4 o;
    o.x = f2bf(fmaxf(v0.x + v1.x + v2.x + v3.x + b.x, 0.f));
    o.y = f2bf(fmaxf(v0.y + v1.y + v2.y + v3.y + b.y, 0.f));
    o.z = f2bf(fmaxf(v0.z + v1.z + v2.z + v3.z + b.z, 0.f));
    o.w = f2bf(fmaxf(v0.w + v1.w + v2.w + v3.w + b.w, 0.f));
    ((ushort4*)out)[gI] = o;
}

// ---------------- pack Wc (21) and Wr (80) transposed into [128][4096] bf16 ------------
__global__ __launch_bounds__(256) void k_pack_w3(const float* __restrict__ Wc,
                                                 const float* __restrict__ Wr,
                                                 unsigned short* __restrict__ W3T) {
    int gI = blockIdx.x * 256 + threadIdx.x;   // 128*4096
    int n = gI >> 12, k = gI & 4095;
    float v = 0.f;
    if (n < 21) v = Wc[k * 21 + n];
    else if (n < 101) v = Wr[k * 80 + (n - 21)];
    W3T[gI] = f2bf(v);
}

// ---------------- 16-partial reduce + softmax(cls) + reg writeout ----------------------
__global__ __launch_bounds__(64) void k_head(const float* __restrict__ acc3,
                                             const float* __restrict__ bc,
                                             const float* __restrict__ br,
                                             float* __restrict__ out) {
    int r = blockIdx.x;          // 1000
    int lane = threadIdx.x;
    float logit = -1e30f;
    if (lane < 21) {
        logit = bc[lane];
#pragma unroll
        for (int z = 0; z < 16; ++z) logit += acc3[z * 131072 + r * 128 + lane];
    }
    float mx = logit;
#pragma unroll
    for (int m = 32; m >= 1; m >>= 1) mx = fmaxf(mx, __shfl_xor(mx, m, 64));
    float e = (lane < 21) ? expf(logit - mx) : 0.f;
    float s = e;
#pragma unroll
    for (int m = 32; m >= 1; m >>= 1) s += __shfl_xor(s, m, 64);
    if (lane < 21) out[r * 21 + lane] = e / s;
    for (int j = lane; j < 80; j += 64) {
        float v = br[j];
#pragma unroll
        for (int z = 0; z < 16; ++z) v += acc3[z * 131072 + r * 128 + 21 + j];
        out[21000 + r * 80 + j] = v;
    }
}

extern "C" void kernel_launch(void* const* d_in, const int* in_sizes, int n_in,
                              void* d_out, int out_size, void* d_ws, size_t ws_size,
                              hipStream_t stream) {
    (void)in_sizes; (void)n_in; (void)out_size; (void)ws_size;
    const float* feats = (const float*)d_in[0];
    const float* props = (const float*)d_in[1];
    const float* W1    = (const float*)d_in[2];
    const float* b1    = (const float*)d_in[3];
    const float* W2    = (const float*)d_in[4];
    const float* b2    = (const float*)d_in[5];
    const float* Wc    = (const float*)d_in[6];
    const float* bc    = (const float*)d_in[7];
    const float* Wr    = (const float*)d_in[8];
    const float* br    = (const float*)d_in[9];
    float* out = (float*)d_out;

    char* ws = (char*)d_ws;
    unsigned short* W1T    = (unsigned short*)ws; ws += (size_t)4096 * 25088 * 2; // 205.5 MB
    unsigned short* W2T    = (unsigned short*)ws; ws += (size_t)4096 * 4096 * 2;  // 33.6 MB
    unsigned short* W3T    = (unsigned short*)ws; ws += (size_t)128 * 4096 * 2;   // 1.05 MB
    unsigned short* featsb = (unsigned short*)ws; ws += (size_t)972800 * 2;       // 1.95 MB
    unsigned short* pooled = (unsigned short*)ws; ws += (size_t)1024 * 25088 * 2; // 51.4 MB
    unsigned short* x1     = (unsigned short*)ws; ws += (size_t)1024 * 4096 * 2;  // 8.4 MB
    unsigned short* x2     = (unsigned short*)ws; ws += (size_t)1024 * 4096 * 2;  // 8.4 MB
    float* accP            = (float*)ws;          ws += (size_t)4 * 1024 * 4096 * 4; // 67.1 MB
    float* acc3P           = accP;  // GEMM3 partials reuse accP (free after bias2)

    k_cvt_feats<<<950, 256, 0, stream>>>(feats, featsb);
    k_roipool<<<1024 * 49, 256, 0, stream>>>(featsb, props, pooled);
    k_transpose_cvt<<<dim3(392, 64), 256, 0, stream>>>(W1, W1T, 25088, 4096);
    k_gemm<<<dim3(32, 8, 4), 256, 0, stream>>>(pooled, W1T, accP, 4096, 25088, 6272, 1024 * 4096);
    k_bias_relu_cvt<<<4096, 256, 0, stream>>>(accP, b1, x1);
    k_transpose_cvt<<<dim3(64, 64), 256, 0, stream>>>(W2, W2T, 4096, 4096);
    k_gemm<<<dim3(32, 8, 4), 256, 0, stream>>>(x1, W2T, accP, 4096, 4096, 1024, 1024 * 4096);
    k_bias_relu_cvt<<<4096, 256, 0, stream>>>(accP, b2, x2);
    k_pack_w3<<<2048, 256, 0, stream>>>(Wc, Wr, W3T);
    k_gemm<<<dim3(1, 8, 16), 256, 0, stream>>>(x2, W3T, acc3P, 128, 4096, 256, 1024 * 128);
    k_head<<<1000, 64, 0, stream>>>(acc3P, bc, br, out);
}